// Round 11
// baseline (111.554 us; speedup 1.0000x reference)
//
#include <hip/hip_runtime.h>

#define IN_CH 96
#define OUT_CH 384
#define THREADS 384

typedef float f32x4 __attribute__((ext_vector_type(4)));
typedef float f32x2 __attribute__((ext_vector_type(2)));

// R8 winner (2ch/thread, 26-float pinned stash, nt stores, grid 768) with ONE
// change: 1-deep software prefetch — next iteration's 3 loads are issued
// BEFORE this iteration's nt store. vmcnt retires in order, so in R8 the
// loads (younger than the store) could not be consumed until the nt store's
// ack returned from the memory system (~3000 cy/iter measured). With the
// prefetch the FIFO is [loads q+1][store q][loads q+2]: the compute wait is
// a counted vmcnt that never drains the store -> store ack off the critical
// path. (R5 tested this idea confounded with plain stores, which are a
// proven 2x loss; this is the clean A/B on the nt base.)
//
// Thread t: p = t%192 -> channels {2p,2p+1} of joint p>>3; rl = t/192.
// Row pair index i covers rows 2i+rl; 12-float x-window, 24 FMA, f32x2 store.
__global__ __launch_bounds__(THREADS, 5) void skel_linear_kernel(
    const float* __restrict__ x,
    const float* __restrict__ weight,
    const float* __restrict__ mask,
    const float* __restrict__ bias,
    float* __restrict__ out,
    int batch)
{
    const int t     = threadIdx.x;
    const int p     = t % 192;         // channel-pair index 0..191
    const int rl    = t / 192;         // 0..1
    const int chan  = p * 2;
    const int joint = p >> 3;
    const int jc    = (joint - 1 < 0) ? 0 : ((joint - 1 > 21) ? 21 : joint - 1);
    const int c0    = jc * 4;          // contiguous 12-col window [c0, c0+12)

    // Masked weights + bias, loaded once (26 floats: proven register-resident).
    float w[2][12];
    float b[2];
#pragma unroll
    for (int j = 0; j < 2; ++j) {
        const size_t row = (size_t)(chan + j) * IN_CH;
#pragma unroll
        for (int c = 0; c < 12; ++c)
            w[j][c] = weight[row + c0 + c] * mask[row + c0 + c];
        b[j] = bias[chan + j];
    }
#pragma unroll
    for (int j = 0; j < 2; ++j) {
#pragma unroll
        for (int c = 0; c < 12; ++c)
            asm volatile("" : "+v"(w[j][c]));
        asm volatile("" : "+v"(b[j]));
    }

    const int npairs = batch >> 1;     // 131072 row-pairs
    const int stride = gridDim.x;

    // Prologue: load pair blockIdx.x.
    int q = blockIdx.x;
    const float* xp = x + (size_t)(q * 2 + rl) * IN_CH + c0;
    f32x4 xa = *reinterpret_cast<const f32x4*>(xp);
    f32x4 xb = *reinterpret_cast<const f32x4*>(xp + 4);
    f32x4 xc = *reinterpret_cast<const f32x4*>(xp + 8);

    while (q < npairs) {
        const int qn = q + stride;
        const int qc = (qn < npairs) ? qn : q;   // clamped prefetch (uniform)
        // Prefetch next pair BEFORE this iteration's store (keeps loads
        // OLDER than the store in the vmcnt FIFO).
        const float* xn = x + (size_t)(qc * 2 + rl) * IN_CH + c0;
        const f32x4 na = *reinterpret_cast<const f32x4*>(xn);
        const f32x4 nb = *reinterpret_cast<const f32x4*>(xn + 4);
        const f32x4 nc = *reinterpret_cast<const f32x4*>(xn + 8);

        f32x2 o2;
#pragma unroll
        for (int j = 0; j < 2; ++j) {
            float acc = b[j];
            acc = fmaf(w[j][0],  xa.x, acc);
            acc = fmaf(w[j][1],  xa.y, acc);
            acc = fmaf(w[j][2],  xa.z, acc);
            acc = fmaf(w[j][3],  xa.w, acc);
            acc = fmaf(w[j][4],  xb.x, acc);
            acc = fmaf(w[j][5],  xb.y, acc);
            acc = fmaf(w[j][6],  xb.z, acc);
            acc = fmaf(w[j][7],  xb.w, acc);
            acc = fmaf(w[j][8],  xc.x, acc);
            acc = fmaf(w[j][9],  xc.y, acc);
            acc = fmaf(w[j][10], xc.z, acc);
            acc = fmaf(w[j][11], xc.w, acc);
            o2[j] = acc;
        }

        __builtin_nontemporal_store(o2,
            reinterpret_cast<f32x2*>(out + (size_t)(q * 2 + rl) * OUT_CH + chan));

        xa = na; xb = nb; xc = nc;
        q = qn;
    }
}

extern "C" void kernel_launch(void* const* d_in, const int* in_sizes, int n_in,
                              void* d_out, int out_size, void* d_ws, size_t ws_size,
                              hipStream_t stream) {
    const float* x      = (const float*)d_in[0];
    const float* weight = (const float*)d_in[1];
    const float* mask   = (const float*)d_in[2];
    const float* bias   = (const float*)d_in[3];
    float* out          = (float*)d_out;

    const int batch = in_sizes[0] / IN_CH;   // 262144
    const int grid  = 768;   // proven best (R4/R7: 768 > 1280)

    skel_linear_kernel<<<grid, THREADS, 0, stream>>>(x, weight, mask, bias, out, batch);
}